// Round 10
// baseline (357.370 us; speedup 1.0000x reference)
//
#include <hip/hip_runtime.h>
#include <hip/hip_bf16.h>

// SingleHeadCausalSelfAttention B=8 S=2048 H=1024 causal.
// R10: TLP experiment. All GEMMs on 256x128 tile, BK=32, 8 waves, 48 KB LDS
// double-buffer -> 2 blocks/CU co-resident (launch_bounds(512,4), acc=64 VGPR).
// 2-step-lead stage schedule, one counted vmcnt(3) per step. 3-bit-equivalent
// swizzle for 64B rows (row&3). QKV 3-wide fused; scores 576 causal tiles;
// pv causal NK with backfill smoothing; no softmax kernel (exp+rowsum).

typedef __bf16 bf16x8 __attribute__((ext_vector_type(8)));
typedef float f32x4 __attribute__((ext_vector_type(4)));

static constexpr int HD = 1024;
static constexpr int BB = 8;
static constexpr int SS = 2048;
static constexpr long long SH = (long long)SS * HD;

__device__ __forceinline__ unsigned short f2bf(float f) {
  unsigned u = __builtin_bit_cast(unsigned, f);
  return (unsigned short)((u + 0x7FFFu + ((u >> 16) & 1u)) >> 16);
}
__device__ __forceinline__ f32x4 mfma16(bf16x8 a, bf16x8 b, f32x4 c) {
  return __builtin_amdgcn_mfma_f32_16x16x32_bf16(a, b, c, 0, 0, 0);
}
__device__ __forceinline__ void gload_lds16(const void* g, void* l) {
  __builtin_amdgcn_global_load_lds(
      (const __attribute__((address_space(1))) void*)g,
      (__attribute__((address_space(3))) void*)l, 16, 0, 0);
}

#define WAIT_LGKM0() do { asm volatile("s_waitcnt lgkmcnt(0)" ::: "memory"); \
  __builtin_amdgcn_sched_barrier(0); } while (0)
#define WAIT_VM(n) do { asm volatile("s_waitcnt vmcnt(" #n ")" ::: "memory"); \
  __builtin_amdgcn_sched_barrier(0); } while (0)

// 64B-row LDS tile, swizzled read: byte = row*64 + (colb ^ ((row&3)<<4))
__device__ __forceinline__ bf16x8 rf(const unsigned short* tile, int row,
                                     int colb) {
  const int byte = row * 64 + (colb ^ ((row & 3) << 4));
  return *reinterpret_cast<const bf16x8*>(
      reinterpret_cast<const char*>(tile) + byte);
}

struct TC {
  int wid, wm, wn, cb, rr, ccl, l16;
  const unsigned short *pA, *pA2, *pB;  // per-thread global srcs (k=0)
};

// A: 256 rows (2 gloads), B: 128 rows (1 gload). Source cols pre-swizzled.
__device__ __forceinline__ TC tc_make(const unsigned short* A,
                                      const unsigned short* B, int m0, int n0,
                                      long long lda, long long ldb) {
  TC t;
  const int tid = threadIdx.x;
  t.wid = tid >> 6;
  const int lane = tid & 63;
  t.wm = t.wid >> 1;       // 0..3 (64-row groups of 256)
  t.wn = t.wid & 1;        // 0..1 (64-col groups of 128)
  t.l16 = lane & 15;
  t.cb = (lane >> 4) * 16; // frag col-byte
  t.rr = (lane >> 4) * 4;
  t.ccl = t.l16;
  const int rowt = tid >> 2;                              // 0..127
  const int colg = (((tid & 3) ^ (rowt & 3)) * 8);        // pre-swizzle
  t.pA = A + (long long)(m0 + rowt) * lda + colg;
  t.pA2 = t.pA + 128 * lda;
  t.pB = B + (long long)(n0 + rowt) * ldb + colg;
  return t;
}

#define STAGE(Abuf, Bbuf, kt) do { \
  gload_lds16(t.pA + (kt), (Abuf) + t.wid * 512); \
  gload_lds16(t.pA2 + (kt), (Abuf) + 4096 + t.wid * 512); \
  gload_lds16(t.pB + (kt), (Bbuf) + t.wid * 512); \
} while (0)

// acc[4][4]: 64x64 per wave. NK = K/32 >= 2.
__device__ __forceinline__ void run_tile(
    const TC& t, int NK, unsigned short* As0, unsigned short* As1,
    unsigned short* Bs0, unsigned short* Bs1, f32x4 (&acc)[4][4]) {
  STAGE(As0, Bs0, 0);
  STAGE(As1, Bs1, 32);
  WAIT_VM(3);
  __builtin_amdgcn_s_barrier();
  for (int k = 0; k < NK; ++k) {
    const unsigned short* A = (k & 1) ? As1 : As0;
    const unsigned short* B = (k & 1) ? Bs1 : Bs0;
    bf16x8 af[4], bf[4];
#pragma unroll
    for (int i = 0; i < 4; ++i)
      af[i] = rf(A, t.wm * 64 + i * 16 + t.l16, t.cb);
#pragma unroll
    for (int i = 0; i < 4; ++i)
      bf[i] = rf(B, t.wn * 64 + i * 16 + t.l16, t.cb);
    WAIT_LGKM0();
    __builtin_amdgcn_s_barrier();   // all waves done reading this buffer
    if (k + 2 < NK) {
      unsigned short* An = (k & 1) ? As1 : As0;
      unsigned short* Bn = (k & 1) ? Bs1 : Bs0;
      STAGE(An, Bn, (long long)(k + 2) * 32);
    }
    __builtin_amdgcn_s_setprio(1);
#pragma unroll
    for (int mi = 0; mi < 4; ++mi)
#pragma unroll
      for (int ni = 0; ni < 4; ++ni)
        acc[mi][ni] = mfma16(af[mi], bf[ni], acc[mi][ni]);
    __builtin_amdgcn_s_setprio(0);
    if (k + 2 < NK) { WAIT_VM(3); } else { WAIT_VM(0); }
    __builtin_amdgcn_s_barrier();
  }
}

#define SHARED_TILES() \
  __shared__ __align__(16) unsigned short As0[8192], As1[8192]; \
  __shared__ __align__(16) unsigned short Bs0[4096], Bs1[4096]

// ---- fused QKV projection: C[16384][3072] -> Q | K | Vt ----
__global__ __launch_bounds__(512, 4) void qkv_kernel(
    const unsigned short* __restrict__ X, const unsigned short* __restrict__ W,
    const float* __restrict__ bq, const float* __restrict__ bk,
    const float* __restrict__ bv, unsigned short* __restrict__ Q,
    unsigned short* __restrict__ K, unsigned short* __restrict__ Vt) {
  SHARED_TILES();
  const int lin = blockIdx.x;                  // 1536
  const int swz = (lin & 7) * 192 + (lin >> 3);
  const int m0 = (swz / 24) * 256, n0 = (swz % 24) * 128;
  TC t = tc_make(X, W, m0, n0, HD, HD);
  f32x4 acc[4][4] = {};
  run_tile(t, 32, As0, As1, Bs0, Bs1, acc);
#pragma unroll
  for (int mi = 0; mi < 4; ++mi)
#pragma unroll
    for (int ni = 0; ni < 4; ++ni) {
      const int gn = n0 + t.wn * 64 + ni * 16 + t.ccl;
      float bias;
      if (gn < 1024) bias = bq[gn];
      else if (gn < 2048) bias = bk[gn - 1024];
      else bias = bv[gn - 2048];
#pragma unroll
      for (int j = 0; j < 4; ++j) {
        const int gm = m0 + t.wm * 64 + mi * 16 + t.rr + j;
        const unsigned short v = f2bf(acc[mi][ni][j] + bias);
        if (gn < 1024) {
          Q[(long long)gm * HD + gn] = v;
        } else if (gn < 2048) {
          K[(long long)gm * HD + (gn - 1024)] = v;
        } else {
          const int b = gm >> 11, s = gm & 2047, d = gn - 2048;
          Vt[b * SH + (long long)d * SS + s] = v;
        }
      }
    }
}

// ---- scores: 256x128 causal tiles (72/batch, 576 blocks); exp + rowsum ----
__global__ __launch_bounds__(512, 4) void scores_kernel(
    const unsigned short* __restrict__ Q, const unsigned short* __restrict__ Km,
    const int* __restrict__ mask, unsigned short* __restrict__ S,
    float* __restrict__ rowsum) {
  SHARED_TILES();
  __shared__ float rsl[512];
  const int lin = blockIdx.x;        // 576
  const long long b = lin & 7;       // batch -> XCD pin
  int tt = lin >> 3;                 // 0..71
  int mt = 0, cum = 0;
  while (tt >= cum + 2 * mt + 2) { cum += 2 * mt + 2; ++mt; }
  const int nt = tt - cum;           // 0..2mt+1
  const int m0 = mt * 256, n0 = nt * 128;
  TC t = tc_make(Q + b * SH, Km + b * SH, m0, n0, HD, HD);
  f32x4 acc[4][4] = {};
  run_tile(t, 32, As0, As1, Bs0, Bs1, acc);

  unsigned short* Sb = S + b * (long long)SS * SS;
  const int* mb = mask + b * SS;
  float* rs = rowsum + b * SS;
#pragma unroll
  for (int mi = 0; mi < 4; ++mi)
#pragma unroll
    for (int j = 0; j < 4; ++j) {
      const int lrow = t.wm * 64 + mi * 16 + t.rr + j;
      const int gm = m0 + lrow;
      float rsum = 0.0f;
#pragma unroll
      for (int ni = 0; ni < 4; ++ni) {
        const int gn = n0 + t.wn * 64 + ni * 16 + t.ccl;
        const bool dead = (gn > gm) || (mb[gn] == 0);
        const float pv = dead ? 0.0f : __expf(acc[mi][ni][j] * 0.03125f);
        Sb[(long long)gm * SS + gn] = f2bf(pv);
        rsum += pv;
      }
#pragma unroll
      for (int o = 1; o < 16; o <<= 1) rsum += __shfl_xor(rsum, o);
      if (t.ccl == 0) rsl[t.wn * 256 + lrow] = rsum;
    }
  __syncthreads();
  const int tid = threadIdx.x;
  if (tid < 256) atomicAdd(&rs[m0 + tid], rsl[tid] + rsl[256 + tid]);
}

// ---- PV: 256x128 tiles, causal NK=8(mt+1); divide by rowsum ----
__global__ __launch_bounds__(512, 4) void pv_kernel(
    const unsigned short* __restrict__ S, const unsigned short* __restrict__ Vt,
    const float* __restrict__ rowsum, unsigned short* __restrict__ AO) {
  SHARED_TILES();
  const int lin = blockIdx.x;        // 512
  const long long b = lin & 7;
  const int r = lin >> 3;            // 0..63
  const int mt = r & 7, nt = r >> 3;
  const int m0 = mt * 256, n0 = nt * 128;
  const int NK = 8 * (mt + 1);
  TC t = tc_make(S + b * (long long)SS * SS, Vt + b * SH, m0, n0, SS, SS);
  f32x4 acc[4][4] = {};
  run_tile(t, NK, As0, As1, Bs0, Bs1, acc);
  const float* rs = rowsum + b * SS;
#pragma unroll
  for (int mi = 0; mi < 4; ++mi)
#pragma unroll
    for (int j = 0; j < 4; ++j) {
      const int gm = m0 + t.wm * 64 + mi * 16 + t.rr + j;
      const float inv = 1.0f / rs[gm];
#pragma unroll
      for (int ni = 0; ni < 4; ++ni) {
        const int gn = n0 + t.wn * 64 + ni * 16 + t.ccl;
        AO[(b * SS + gm) * (long long)HD + gn] = f2bf(acc[mi][ni][j] * inv);
      }
    }
}

// ---- output projection: f32 out ----
__global__ __launch_bounds__(512, 4) void oproj_kernel(
    const unsigned short* __restrict__ AO, const unsigned short* __restrict__ W,
    const float* __restrict__ bo, float* __restrict__ out) {
  SHARED_TILES();
  const int lin = blockIdx.x;        // 512
  const int swz = (lin & 7) * 64 + (lin >> 3);
  const int m0 = (swz >> 3) * 256, n0 = (swz & 7) * 128;
  TC t = tc_make(AO, W, m0, n0, HD, HD);
  f32x4 acc[4][4] = {};
  run_tile(t, 32, As0, As1, Bs0, Bs1, acc);
#pragma unroll
  for (int mi = 0; mi < 4; ++mi)
#pragma unroll
    for (int ni = 0; ni < 4; ++ni) {
      const int gn = n0 + t.wn * 64 + ni * 16 + t.ccl;
      const float bias = bo[gn];
#pragma unroll
      for (int j = 0; j < 4; ++j) {
        const int gm = m0 + t.wm * 64 + mi * 16 + t.rr + j;
        out[(long long)gm * HD + gn] = acc[mi][ni][j] + bias;
      }
    }
}

// ---- single cast dispatch: x + 4 weights -> bf16, rowsum -> 0 ----
__global__ __launch_bounds__(256) void cast_all(
    const float* __restrict__ x, const float* __restrict__ wq,
    const float* __restrict__ wk, const float* __restrict__ wv,
    const float* __restrict__ wo, unsigned short* __restrict__ xb,
    unsigned short* __restrict__ wqkvb, unsigned short* __restrict__ wob,
    float* __restrict__ rowsum) {
  const int NX4 = (int)((long long)BB * SS * HD / 4);
  const int W4 = HD * HD / 4;
  const int RS4 = BB * SS / 4;
  const int TOT = NX4 + 4 * W4 + RS4;
  int idx = blockIdx.x * blockDim.x + threadIdx.x;
  const int stride = gridDim.x * blockDim.x;
  for (int u = idx; u < TOT; u += stride) {
    if (u >= NX4 + 4 * W4) {
      *reinterpret_cast<float4*>(rowsum + (u - NX4 - 4 * W4) * 4) =
          make_float4(0.f, 0.f, 0.f, 0.f);
      continue;
    }
    const float* src;
    unsigned short* dst;
    int off;
    if (u < NX4) {
      src = x; dst = xb; off = u;
    } else {
      const int v = u - NX4;
      const int seg = v >> 18;
      off = v & (W4 - 1);
      if (seg == 0) { src = wq; dst = wqkvb; }
      else if (seg == 1) { src = wk; dst = wqkvb + HD * HD; }
      else if (seg == 2) { src = wv; dst = wqkvb + 2 * HD * HD; }
      else { src = wo; dst = wob; }
    }
    float4 f = *reinterpret_cast<const float4*>(src + off * 4);
    ushort4 o;
    o.x = f2bf(f.x); o.y = f2bf(f.y); o.z = f2bf(f.z); o.w = f2bf(f.w);
    *reinterpret_cast<ushort4*>(dst + off * 4) = o;
  }
}

extern "C" void kernel_launch(void* const* d_in, const int* in_sizes, int n_in,
                              void* d_out, int out_size, void* d_ws, size_t ws_size,
                              hipStream_t stream) {
  const float* x = (const float*)d_in[0];
  const int* amask = (const int*)d_in[1];
  const float* wq = (const float*)d_in[2];
  const float* bq = (const float*)d_in[3];
  const float* wk = (const float*)d_in[4];
  const float* bk = (const float*)d_in[5];
  const float* wv = (const float*)d_in[6];
  const float* bv = (const float*)d_in[7];
  const float* wo = (const float*)d_in[8];
  const float* bo = (const float*)d_in[9];
  float* out = (float*)d_out;

  const long long NX = (long long)BB * SS * HD;
  char* p = (char*)d_ws;
  unsigned short* xb = (unsigned short*)p;     p += NX * 2;
  unsigned short* wqkvb = (unsigned short*)p;  p += 3LL * HD * HD * 2;
  unsigned short* wob = (unsigned short*)p;    p += (long long)HD * HD * 2;
  unsigned short* Qb = (unsigned short*)p;     p += NX * 2;
  unsigned short* Kb = (unsigned short*)p;     p += NX * 2;
  unsigned short* Vtb = (unsigned short*)p;    p += NX * 2;  // [b][d][s]
  unsigned short* Sb = (unsigned short*)p;     p += (long long)BB * SS * SS * 2;
  float* rowsum = (float*)p;                   p += (long long)BB * SS * 4;
  unsigned short* AOb = xb;  // alias: x dead after qkv

  cast_all<<<dim3(2048), 256, 0, stream>>>(x, wq, wk, wv, wo, xb, wqkvb, wob,
                                           rowsum);

  qkv_kernel<<<dim3(1536), 512, 0, stream>>>(xb, wqkvb, bq, bk, bv, Qb, Kb,
                                             Vtb);

  scores_kernel<<<dim3(576), 512, 0, stream>>>(Qb, Kb, amask, Sb, rowsum);
  pv_kernel<<<dim3(512), 512, 0, stream>>>(Sb, Vtb, rowsum, AOb);

  oproj_kernel<<<dim3(512), 512, 0, stream>>>(AOb, wob, bo, out);
}

// Round 11
// 348.098 us; speedup vs baseline: 1.0266x; 1.0266x over previous
//
#include <hip/hip_runtime.h>
#include <hip/hip_bf16.h>

// SingleHeadCausalSelfAttention B=8 S=2048 H=1024 causal.
// R11 = R10 + two fixes:
// (1) LDS swizzle bit corrected: (row>>1)&3 (row&3's low bit was correlated
//     with the even/odd bank-half parity of 64B rows -> 4-way conflict).
// (2) pv block pairing: consecutive blocks get mt=q / 7-q -> uniform CU load.
// Structure: 256x128 tile, BK=32, 8 waves, 48KB LDS dbuf, 2 blocks/CU.

typedef __bf16 bf16x8 __attribute__((ext_vector_type(8)));
typedef float f32x4 __attribute__((ext_vector_type(4)));

static constexpr int HD = 1024;
static constexpr int BB = 8;
static constexpr int SS = 2048;
static constexpr long long SH = (long long)SS * HD;

__device__ __forceinline__ unsigned short f2bf(float f) {
  unsigned u = __builtin_bit_cast(unsigned, f);
  return (unsigned short)((u + 0x7FFFu + ((u >> 16) & 1u)) >> 16);
}
__device__ __forceinline__ f32x4 mfma16(bf16x8 a, bf16x8 b, f32x4 c) {
  return __builtin_amdgcn_mfma_f32_16x16x32_bf16(a, b, c, 0, 0, 0);
}
__device__ __forceinline__ void gload_lds16(const void* g, void* l) {
  __builtin_amdgcn_global_load_lds(
      (const __attribute__((address_space(1))) void*)g,
      (__attribute__((address_space(3))) void*)l, 16, 0, 0);
}

#define WAIT_LGKM0() do { asm volatile("s_waitcnt lgkmcnt(0)" ::: "memory"); \
  __builtin_amdgcn_sched_barrier(0); } while (0)
#define WAIT_VM(n) do { asm volatile("s_waitcnt vmcnt(" #n ")" ::: "memory"); \
  __builtin_amdgcn_sched_barrier(0); } while (0)

// 64B-row LDS tile, swizzled read: byte = row*64 + (colb ^ (((row>>1)&3)<<4)).
// Even rows (bank half 0) spread slots 0..3 as row/2 cycles -> 2-way (free).
__device__ __forceinline__ bf16x8 rf(const unsigned short* tile, int row,
                                     int colb) {
  const int byte = row * 64 + (colb ^ (((row >> 1) & 3) << 4));
  return *reinterpret_cast<const bf16x8*>(
      reinterpret_cast<const char*>(tile) + byte);
}

struct TC {
  int wid, wm, wn, cb, rr, ccl, l16;
  const unsigned short *pA, *pA2, *pB;  // per-thread global srcs (k=0)
};

// A: 256 rows (2 gloads), B: 128 rows (1 gload). Source cols pre-swizzled
// with the same involution the read applies.
__device__ __forceinline__ TC tc_make(const unsigned short* A,
                                      const unsigned short* B, int m0, int n0,
                                      long long lda, long long ldb) {
  TC t;
  const int tid = threadIdx.x;
  t.wid = tid >> 6;
  const int lane = tid & 63;
  t.wm = t.wid >> 1;       // 0..3 (64-row groups of 256)
  t.wn = t.wid & 1;        // 0..1 (64-col groups of 128)
  t.l16 = lane & 15;
  t.cb = (lane >> 4) * 16; // frag col-byte
  t.rr = (lane >> 4) * 4;
  t.ccl = t.l16;
  const int rowt = tid >> 2;                                  // 0..127
  const int colg = (((tid & 3) ^ ((rowt >> 1) & 3)) * 8);     // pre-swizzle
  t.pA = A + (long long)(m0 + rowt) * lda + colg;
  t.pA2 = t.pA + 128 * lda;
  t.pB = B + (long long)(n0 + rowt) * ldb + colg;
  return t;
}

#define STAGE(Abuf, Bbuf, kt) do { \
  gload_lds16(t.pA + (kt), (Abuf) + t.wid * 512); \
  gload_lds16(t.pA2 + (kt), (Abuf) + 4096 + t.wid * 512); \
  gload_lds16(t.pB + (kt), (Bbuf) + t.wid * 512); \
} while (0)

// acc[4][4]: 64x64 per wave. NK = K/32 >= 2.
__device__ __forceinline__ void run_tile(
    const TC& t, int NK, unsigned short* As0, unsigned short* As1,
    unsigned short* Bs0, unsigned short* Bs1, f32x4 (&acc)[4][4]) {
  STAGE(As0, Bs0, 0);
  STAGE(As1, Bs1, 32);
  WAIT_VM(3);
  __builtin_amdgcn_s_barrier();
  for (int k = 0; k < NK; ++k) {
    const unsigned short* A = (k & 1) ? As1 : As0;
    const unsigned short* B = (k & 1) ? Bs1 : Bs0;
    bf16x8 af[4], bf[4];
#pragma unroll
    for (int i = 0; i < 4; ++i)
      af[i] = rf(A, t.wm * 64 + i * 16 + t.l16, t.cb);
#pragma unroll
    for (int i = 0; i < 4; ++i)
      bf[i] = rf(B, t.wn * 64 + i * 16 + t.l16, t.cb);
    WAIT_LGKM0();
    __builtin_amdgcn_s_barrier();   // all waves done reading this buffer
    if (k + 2 < NK) {
      unsigned short* An = (k & 1) ? As1 : As0;
      unsigned short* Bn = (k & 1) ? Bs1 : Bs0;
      STAGE(An, Bn, (long long)(k + 2) * 32);
    }
    __builtin_amdgcn_s_setprio(1);
#pragma unroll
    for (int mi = 0; mi < 4; ++mi)
#pragma unroll
      for (int ni = 0; ni < 4; ++ni)
        acc[mi][ni] = mfma16(af[mi], bf[ni], acc[mi][ni]);
    __builtin_amdgcn_s_setprio(0);
    if (k + 2 < NK) { WAIT_VM(3); } else { WAIT_VM(0); }
    __builtin_amdgcn_s_barrier();
  }
}

#define SHARED_TILES() \
  __shared__ __align__(16) unsigned short As0[8192], As1[8192]; \
  __shared__ __align__(16) unsigned short Bs0[4096], Bs1[4096]

// ---- fused QKV projection: C[16384][3072] -> Q | K | Vt ----
__global__ __launch_bounds__(512, 4) void qkv_kernel(
    const unsigned short* __restrict__ X, const unsigned short* __restrict__ W,
    const float* __restrict__ bq, const float* __restrict__ bk,
    const float* __restrict__ bv, unsigned short* __restrict__ Q,
    unsigned short* __restrict__ K, unsigned short* __restrict__ Vt) {
  SHARED_TILES();
  const int lin = blockIdx.x;                  // 1536
  const int swz = (lin & 7) * 192 + (lin >> 3);
  const int m0 = (swz / 24) * 256, n0 = (swz % 24) * 128;
  TC t = tc_make(X, W, m0, n0, HD, HD);
  f32x4 acc[4][4] = {};
  run_tile(t, 32, As0, As1, Bs0, Bs1, acc);
#pragma unroll
  for (int mi = 0; mi < 4; ++mi)
#pragma unroll
    for (int ni = 0; ni < 4; ++ni) {
      const int gn = n0 + t.wn * 64 + ni * 16 + t.ccl;
      float bias;
      if (gn < 1024) bias = bq[gn];
      else if (gn < 2048) bias = bk[gn - 1024];
      else bias = bv[gn - 2048];
#pragma unroll
      for (int j = 0; j < 4; ++j) {
        const int gm = m0 + t.wm * 64 + mi * 16 + t.rr + j;
        const unsigned short v = f2bf(acc[mi][ni][j] + bias);
        if (gn < 1024) {
          Q[(long long)gm * HD + gn] = v;
        } else if (gn < 2048) {
          K[(long long)gm * HD + (gn - 1024)] = v;
        } else {
          const int b = gm >> 11, s = gm & 2047, d = gn - 2048;
          Vt[b * SH + (long long)d * SS + s] = v;
        }
      }
    }
}

// ---- scores: 256x128 causal tiles (72/batch, 576 blocks); exp + rowsum ----
__global__ __launch_bounds__(512, 4) void scores_kernel(
    const unsigned short* __restrict__ Q, const unsigned short* __restrict__ Km,
    const int* __restrict__ mask, unsigned short* __restrict__ S,
    float* __restrict__ rowsum) {
  SHARED_TILES();
  __shared__ float rsl[512];
  const int lin = blockIdx.x;        // 576
  const long long b = lin & 7;       // batch -> XCD pin
  int tt = lin >> 3;                 // 0..71
  int mt = 0, cum = 0;
  while (tt >= cum + 2 * mt + 2) { cum += 2 * mt + 2; ++mt; }
  const int nt = tt - cum;           // 0..2mt+1
  const int m0 = mt * 256, n0 = nt * 128;
  TC t = tc_make(Q + b * SH, Km + b * SH, m0, n0, HD, HD);
  f32x4 acc[4][4] = {};
  run_tile(t, 32, As0, As1, Bs0, Bs1, acc);

  unsigned short* Sb = S + b * (long long)SS * SS;
  const int* mb = mask + b * SS;
  float* rs = rowsum + b * SS;
#pragma unroll
  for (int mi = 0; mi < 4; ++mi)
#pragma unroll
    for (int j = 0; j < 4; ++j) {
      const int lrow = t.wm * 64 + mi * 16 + t.rr + j;
      const int gm = m0 + lrow;
      float rsum = 0.0f;
#pragma unroll
      for (int ni = 0; ni < 4; ++ni) {
        const int gn = n0 + t.wn * 64 + ni * 16 + t.ccl;
        const bool dead = (gn > gm) || (mb[gn] == 0);
        const float pv = dead ? 0.0f : __expf(acc[mi][ni][j] * 0.03125f);
        Sb[(long long)gm * SS + gn] = f2bf(pv);
        rsum += pv;
      }
#pragma unroll
      for (int o = 1; o < 16; o <<= 1) rsum += __shfl_xor(rsum, o);
      if (t.ccl == 0) rsl[t.wn * 256 + lrow] = rsum;
    }
  __syncthreads();
  const int tid = threadIdx.x;
  if (tid < 256) atomicAdd(&rs[m0 + tid], rsl[tid] + rsl[256 + tid]);
}

// ---- PV: 256x128 tiles, causal NK=8(mt+1); mt paired q/(7-q) across
// consecutive blocks so each CU's 2 blocks sum to uniform 72 K-steps ----
__global__ __launch_bounds__(512, 4) void pv_kernel(
    const unsigned short* __restrict__ S, const unsigned short* __restrict__ Vt,
    const float* __restrict__ rowsum, unsigned short* __restrict__ AO) {
  SHARED_TILES();
  const int lin = blockIdx.x;        // 512
  const long long b = lin & 7;
  const int r = lin >> 3;            // 0..63
  const int jp = r >> 1, par = r & 1;
  const int nt = jp >> 2;            // 0..7
  const int q = jp & 3;              // 0..3
  const int mt = par ? 7 - q : q;    // pair sums to 7
  const int m0 = mt * 256, n0 = nt * 128;
  const int NK = 8 * (mt + 1);
  TC t = tc_make(S + b * (long long)SS * SS, Vt + b * SH, m0, n0, SS, SS);
  f32x4 acc[4][4] = {};
  run_tile(t, NK, As0, As1, Bs0, Bs1, acc);
  const float* rs = rowsum + b * SS;
#pragma unroll
  for (int mi = 0; mi < 4; ++mi)
#pragma unroll
    for (int j = 0; j < 4; ++j) {
      const int gm = m0 + t.wm * 64 + mi * 16 + t.rr + j;
      const float inv = 1.0f / rs[gm];
#pragma unroll
      for (int ni = 0; ni < 4; ++ni) {
        const int gn = n0 + t.wn * 64 + ni * 16 + t.ccl;
        AO[(b * SS + gm) * (long long)HD + gn] = f2bf(acc[mi][ni][j] * inv);
      }
    }
}

// ---- output projection: f32 out ----
__global__ __launch_bounds__(512, 4) void oproj_kernel(
    const unsigned short* __restrict__ AO, const unsigned short* __restrict__ W,
    const float* __restrict__ bo, float* __restrict__ out) {
  SHARED_TILES();
  const int lin = blockIdx.x;        // 512
  const int swz = (lin & 7) * 64 + (lin >> 3);
  const int m0 = (swz >> 3) * 256, n0 = (swz & 7) * 128;
  TC t = tc_make(AO, W, m0, n0, HD, HD);
  f32x4 acc[4][4] = {};
  run_tile(t, 32, As0, As1, Bs0, Bs1, acc);
#pragma unroll
  for (int mi = 0; mi < 4; ++mi)
#pragma unroll
    for (int ni = 0; ni < 4; ++ni) {
      const int gn = n0 + t.wn * 64 + ni * 16 + t.ccl;
      const float bias = bo[gn];
#pragma unroll
      for (int j = 0; j < 4; ++j) {
        const int gm = m0 + t.wm * 64 + mi * 16 + t.rr + j;
        out[(long long)gm * HD + gn] = acc[mi][ni][j] + bias;
      }
    }
}

// ---- single cast dispatch: x + 4 weights -> bf16, rowsum -> 0 ----
__global__ __launch_bounds__(256) void cast_all(
    const float* __restrict__ x, const float* __restrict__ wq,
    const float* __restrict__ wk, const float* __restrict__ wv,
    const float* __restrict__ wo, unsigned short* __restrict__ xb,
    unsigned short* __restrict__ wqkvb, unsigned short* __restrict__ wob,
    float* __restrict__ rowsum) {
  const int NX4 = (int)((long long)BB * SS * HD / 4);
  const int W4 = HD * HD / 4;
  const int RS4 = BB * SS / 4;
  const int TOT = NX4 + 4 * W4 + RS4;
  int idx = blockIdx.x * blockDim.x + threadIdx.x;
  const int stride = gridDim.x * blockDim.x;
  for (int u = idx; u < TOT; u += stride) {
    if (u >= NX4 + 4 * W4) {
      *reinterpret_cast<float4*>(rowsum + (u - NX4 - 4 * W4) * 4) =
          make_float4(0.f, 0.f, 0.f, 0.f);
      continue;
    }
    const float* src;
    unsigned short* dst;
    int off;
    if (u < NX4) {
      src = x; dst = xb; off = u;
    } else {
      const int v = u - NX4;
      const int seg = v >> 18;
      off = v & (W4 - 1);
      if (seg == 0) { src = wq; dst = wqkvb; }
      else if (seg == 1) { src = wk; dst = wqkvb + HD * HD; }
      else if (seg == 2) { src = wv; dst = wqkvb + 2 * HD * HD; }
      else { src = wo; dst = wob; }
    }
    float4 f = *reinterpret_cast<const float4*>(src + off * 4);
    ushort4 o;
    o.x = f2bf(f.x); o.y = f2bf(f.y); o.z = f2bf(f.z); o.w = f2bf(f.w);
    *reinterpret_cast<ushort4*>(dst + off * 4) = o;
  }
}

extern "C" void kernel_launch(void* const* d_in, const int* in_sizes, int n_in,
                              void* d_out, int out_size, void* d_ws, size_t ws_size,
                              hipStream_t stream) {
  const float* x = (const float*)d_in[0];
  const int* amask = (const int*)d_in[1];
  const float* wq = (const float*)d_in[2];
  const float* bq = (const float*)d_in[3];
  const float* wk = (const float*)d_in[4];
  const float* bk = (const float*)d_in[5];
  const float* wv = (const float*)d_in[6];
  const float* bv = (const float*)d_in[7];
  const float* wo = (const float*)d_in[8];
  const float* bo = (const float*)d_in[9];
  float* out = (float*)d_out;

  const long long NX = (long long)BB * SS * HD;
  char* p = (char*)d_ws;
  unsigned short* xb = (unsigned short*)p;     p += NX * 2;
  unsigned short* wqkvb = (unsigned short*)p;  p += 3LL * HD * HD * 2;
  unsigned short* wob = (unsigned short*)p;    p += (long long)HD * HD * 2;
  unsigned short* Qb = (unsigned short*)p;     p += NX * 2;
  unsigned short* Kb = (unsigned short*)p;     p += NX * 2;
  unsigned short* Vtb = (unsigned short*)p;    p += NX * 2;  // [b][d][s]
  unsigned short* Sb = (unsigned short*)p;     p += (long long)BB * SS * SS * 2;
  float* rowsum = (float*)p;                   p += (long long)BB * SS * 4;
  unsigned short* AOb = xb;  // alias: x dead after qkv

  cast_all<<<dim3(2048), 256, 0, stream>>>(x, wq, wk, wv, wo, xb, wqkvb, wob,
                                           rowsum);

  qkv_kernel<<<dim3(1536), 512, 0, stream>>>(xb, wqkvb, bq, bk, bv, Qb, Kb,
                                             Vtb);

  scores_kernel<<<dim3(576), 512, 0, stream>>>(Qb, Kb, amask, Sb, rowsum);
  pv_kernel<<<dim3(512), 512, 0, stream>>>(Sb, Vtb, rowsum, AOb);

  oproj_kernel<<<dim3(512), 512, 0, stream>>>(AOb, wob, bo, out);
}

// Round 12
// 338.720 us; speedup vs baseline: 1.0551x; 1.0277x over previous
//
#include <hip/hip_runtime.h>
#include <hip/hip_bf16.h>

// SingleHeadCausalSelfAttention B=8 S=2048 H=1024 causal.
// R12 = R11 with the K-loop rebuilt on a 3-deep LDS rotation:
//   stage target (k+2)%3 is disjoint from read buffer k%3 and (k+1)%3, so
//   stage issues right after lgkmcnt(0) and ONE barrier per K-step suffices
//   (was 2). 72KB LDS, still 2 blocks/CU. Swizzle (row>>1)&3 kept (conflicts=0).

typedef __bf16 bf16x8 __attribute__((ext_vector_type(8)));
typedef float f32x4 __attribute__((ext_vector_type(4)));

static constexpr int HD = 1024;
static constexpr int BB = 8;
static constexpr int SS = 2048;
static constexpr long long SH = (long long)SS * HD;

__device__ __forceinline__ unsigned short f2bf(float f) {
  unsigned u = __builtin_bit_cast(unsigned, f);
  return (unsigned short)((u + 0x7FFFu + ((u >> 16) & 1u)) >> 16);
}
__device__ __forceinline__ f32x4 mfma16(bf16x8 a, bf16x8 b, f32x4 c) {
  return __builtin_amdgcn_mfma_f32_16x16x32_bf16(a, b, c, 0, 0, 0);
}
__device__ __forceinline__ void gload_lds16(const void* g, void* l) {
  __builtin_amdgcn_global_load_lds(
      (const __attribute__((address_space(1))) void*)g,
      (__attribute__((address_space(3))) void*)l, 16, 0, 0);
}

#define WAIT_LGKM0() do { asm volatile("s_waitcnt lgkmcnt(0)" ::: "memory"); \
  __builtin_amdgcn_sched_barrier(0); } while (0)
#define WAIT_VM(n) do { asm volatile("s_waitcnt vmcnt(" #n ")" ::: "memory"); \
  __builtin_amdgcn_sched_barrier(0); } while (0)

// 64B-row LDS tile, swizzled read: byte = row*64 + (colb ^ (((row>>1)&3)<<4)).
__device__ __forceinline__ bf16x8 rf(const unsigned short* tile, int row,
                                     int colb) {
  const int byte = row * 64 + (colb ^ (((row >> 1) & 3) << 4));
  return *reinterpret_cast<const bf16x8*>(
      reinterpret_cast<const char*>(tile) + byte);
}

struct TC {
  int wid, wm, wn, cb, rr, ccl, l16;
  const unsigned short *pA, *pA2, *pB;  // per-thread global srcs (k=0)
};

// A: 256 rows (2 gloads), B: 128 rows (1 gload). Source cols pre-swizzled
// with the same involution the read applies.
__device__ __forceinline__ TC tc_make(const unsigned short* A,
                                      const unsigned short* B, int m0, int n0,
                                      long long lda, long long ldb) {
  TC t;
  const int tid = threadIdx.x;
  t.wid = tid >> 6;
  const int lane = tid & 63;
  t.wm = t.wid >> 1;       // 0..3 (64-row groups of 256)
  t.wn = t.wid & 1;        // 0..1 (64-col groups of 128)
  t.l16 = lane & 15;
  t.cb = (lane >> 4) * 16; // frag col-byte
  t.rr = (lane >> 4) * 4;
  t.ccl = t.l16;
  const int rowt = tid >> 2;                                  // 0..127
  const int colg = (((tid & 3) ^ ((rowt >> 1) & 3)) * 8);     // pre-swizzle
  t.pA = A + (long long)(m0 + rowt) * lda + colg;
  t.pA2 = t.pA + 128 * lda;
  t.pB = B + (long long)(n0 + rowt) * ldb + colg;
  return t;
}

#define STAGE(Abuf, Bbuf, kt) do { \
  gload_lds16(t.pA + (kt), (Abuf) + t.wid * 512); \
  gload_lds16(t.pA2 + (kt), (Abuf) + 4096 + t.wid * 512); \
  gload_lds16(t.pB + (kt), (Bbuf) + t.wid * 512); \
} while (0)

// acc[4][4]: 64x64 per wave. NK >= 2. 3-deep rotation, 1 barrier per step.
__device__ __forceinline__ void run_tile(
    const TC& t, int NK, unsigned short* A0, unsigned short* A1,
    unsigned short* A2, unsigned short* B0, unsigned short* B1,
    unsigned short* B2, f32x4 (&acc)[4][4]) {
  STAGE(A0, B0, 0);
  STAGE(A1, B1, 32);
  WAIT_VM(3);            // retire k=0's loads
  __builtin_amdgcn_s_barrier();
  unsigned short *Ar = A0, *Br = B0;   // read buffer (k)
  unsigned short *An = A1, *Bn = B1;   // next buffer (k+1, in flight)
  unsigned short *Aw = A2, *Bw = B2;   // write buffer (k+2 target)
  for (int k = 0; k < NK; ++k) {
    bf16x8 af[4], bf[4];
#pragma unroll
    for (int i = 0; i < 4; ++i)
      af[i] = rf(Ar, t.wm * 64 + i * 16 + t.l16, t.cb);
#pragma unroll
    for (int i = 0; i < 4; ++i)
      bf[i] = rf(Br, t.wn * 64 + i * 16 + t.l16, t.cb);
    WAIT_LGKM0();          // own reads of Ar/Br landed in regs
    if (k + 2 < NK) STAGE(Aw, Bw, (long long)(k + 2) * 32);
    __builtin_amdgcn_s_setprio(1);
#pragma unroll
    for (int mi = 0; mi < 4; ++mi)
#pragma unroll
      for (int ni = 0; ni < 4; ++ni)
        acc[mi][ni] = mfma16(af[mi], bf[ni], acc[mi][ni]);
    __builtin_amdgcn_s_setprio(0);
    if (k + 1 < NK) {
      if (k + 2 < NK) { WAIT_VM(3); } else { WAIT_VM(0); }  // retire k+1 loads
      __builtin_amdgcn_s_barrier();
      // rotate read<-next<-write<-read
      unsigned short* ta = Ar; Ar = An; An = Aw; Aw = ta;
      unsigned short* tb = Br; Br = Bn; Bn = Bw; Bw = tb;
    }
  }
}

#define SHARED_TILES() \
  __shared__ __align__(16) unsigned short As0[8192], As1[8192], As2[8192]; \
  __shared__ __align__(16) unsigned short Bs0[4096], Bs1[4096], Bs2[4096]

// ---- fused QKV projection: C[16384][3072] -> Q | K | Vt ----
__global__ __launch_bounds__(512, 4) void qkv_kernel(
    const unsigned short* __restrict__ X, const unsigned short* __restrict__ W,
    const float* __restrict__ bq, const float* __restrict__ bk,
    const float* __restrict__ bv, unsigned short* __restrict__ Q,
    unsigned short* __restrict__ K, unsigned short* __restrict__ Vt) {
  SHARED_TILES();
  const int lin = blockIdx.x;                  // 1536
  const int swz = (lin & 7) * 192 + (lin >> 3);
  const int m0 = (swz / 24) * 256, n0 = (swz % 24) * 128;
  TC t = tc_make(X, W, m0, n0, HD, HD);
  f32x4 acc[4][4] = {};
  run_tile(t, 32, As0, As1, As2, Bs0, Bs1, Bs2, acc);
#pragma unroll
  for (int mi = 0; mi < 4; ++mi)
#pragma unroll
    for (int ni = 0; ni < 4; ++ni) {
      const int gn = n0 + t.wn * 64 + ni * 16 + t.ccl;
      float bias;
      if (gn < 1024) bias = bq[gn];
      else if (gn < 2048) bias = bk[gn - 1024];
      else bias = bv[gn - 2048];
#pragma unroll
      for (int j = 0; j < 4; ++j) {
        const int gm = m0 + t.wm * 64 + mi * 16 + t.rr + j;
        const unsigned short v = f2bf(acc[mi][ni][j] + bias);
        if (gn < 1024) {
          Q[(long long)gm * HD + gn] = v;
        } else if (gn < 2048) {
          K[(long long)gm * HD + (gn - 1024)] = v;
        } else {
          const int b = gm >> 11, s = gm & 2047, d = gn - 2048;
          Vt[b * SH + (long long)d * SS + s] = v;
        }
      }
    }
}

// ---- scores: 256x128 causal tiles (72/batch, 576 blocks); exp + rowsum ----
__global__ __launch_bounds__(512, 4) void scores_kernel(
    const unsigned short* __restrict__ Q, const unsigned short* __restrict__ Km,
    const int* __restrict__ mask, unsigned short* __restrict__ S,
    float* __restrict__ rowsum) {
  SHARED_TILES();
  __shared__ float rsl[512];
  const int lin = blockIdx.x;        // 576
  const long long b = lin & 7;       // batch -> XCD pin
  int tt = lin >> 3;                 // 0..71
  int mt = 0, cum = 0;
  while (tt >= cum + 2 * mt + 2) { cum += 2 * mt + 2; ++mt; }
  const int nt = tt - cum;           // 0..2mt+1
  const int m0 = mt * 256, n0 = nt * 128;
  TC t = tc_make(Q + b * SH, Km + b * SH, m0, n0, HD, HD);
  f32x4 acc[4][4] = {};
  run_tile(t, 32, As0, As1, As2, Bs0, Bs1, Bs2, acc);

  unsigned short* Sb = S + b * (long long)SS * SS;
  const int* mb = mask + b * SS;
  float* rs = rowsum + b * SS;
#pragma unroll
  for (int mi = 0; mi < 4; ++mi)
#pragma unroll
    for (int j = 0; j < 4; ++j) {
      const int lrow = t.wm * 64 + mi * 16 + t.rr + j;
      const int gm = m0 + lrow;
      float rsum = 0.0f;
#pragma unroll
      for (int ni = 0; ni < 4; ++ni) {
        const int gn = n0 + t.wn * 64 + ni * 16 + t.ccl;
        const bool dead = (gn > gm) || (mb[gn] == 0);
        const float pv = dead ? 0.0f : __expf(acc[mi][ni][j] * 0.03125f);
        Sb[(long long)gm * SS + gn] = f2bf(pv);
        rsum += pv;
      }
#pragma unroll
      for (int o = 1; o < 16; o <<= 1) rsum += __shfl_xor(rsum, o);
      if (t.ccl == 0) rsl[t.wn * 256 + lrow] = rsum;
    }
  __syncthreads();
  const int tid = threadIdx.x;
  if (tid < 256) atomicAdd(&rs[m0 + tid], rsl[tid] + rsl[256 + tid]);
}

// ---- PV: 256x128 tiles, causal NK=8(mt+1); mt paired q/(7-q) across
// consecutive blocks so each CU's 2 blocks sum to uniform 72 K-steps ----
__global__ __launch_bounds__(512, 4) void pv_kernel(
    const unsigned short* __restrict__ S, const unsigned short* __restrict__ Vt,
    const float* __restrict__ rowsum, unsigned short* __restrict__ AO) {
  SHARED_TILES();
  const int lin = blockIdx.x;        // 512
  const long long b = lin & 7;
  const int r = lin >> 3;            // 0..63
  const int jp = r >> 1, par = r & 1;
  const int nt = jp >> 2;            // 0..7
  const int q = jp & 3;              // 0..3
  const int mt = par ? 7 - q : q;    // pair sums to 7
  const int m0 = mt * 256, n0 = nt * 128;
  const int NK = 8 * (mt + 1);
  TC t = tc_make(S + b * (long long)SS * SS, Vt + b * SH, m0, n0, SS, SS);
  f32x4 acc[4][4] = {};
  run_tile(t, NK, As0, As1, As2, Bs0, Bs1, Bs2, acc);
  const float* rs = rowsum + b * SS;
#pragma unroll
  for (int mi = 0; mi < 4; ++mi)
#pragma unroll
    for (int j = 0; j < 4; ++j) {
      const int gm = m0 + t.wm * 64 + mi * 16 + t.rr + j;
      const float inv = 1.0f / rs[gm];
#pragma unroll
      for (int ni = 0; ni < 4; ++ni) {
        const int gn = n0 + t.wn * 64 + ni * 16 + t.ccl;
        AO[(b * SS + gm) * (long long)HD + gn] = f2bf(acc[mi][ni][j] * inv);
      }
    }
}

// ---- output projection: f32 out ----
__global__ __launch_bounds__(512, 4) void oproj_kernel(
    const unsigned short* __restrict__ AO, const unsigned short* __restrict__ W,
    const float* __restrict__ bo, float* __restrict__ out) {
  SHARED_TILES();
  const int lin = blockIdx.x;        // 512
  const int swz = (lin & 7) * 64 + (lin >> 3);
  const int m0 = (swz >> 3) * 256, n0 = (swz & 7) * 128;
  TC t = tc_make(AO, W, m0, n0, HD, HD);
  f32x4 acc[4][4] = {};
  run_tile(t, 32, As0, As1, As2, Bs0, Bs1, Bs2, acc);
#pragma unroll
  for (int mi = 0; mi < 4; ++mi)
#pragma unroll
    for (int ni = 0; ni < 4; ++ni) {
      const int gn = n0 + t.wn * 64 + ni * 16 + t.ccl;
      const float bias = bo[gn];
#pragma unroll
      for (int j = 0; j < 4; ++j) {
        const int gm = m0 + t.wm * 64 + mi * 16 + t.rr + j;
        out[(long long)gm * HD + gn] = acc[mi][ni][j] + bias;
      }
    }
}

// ---- single cast dispatch: x + 4 weights -> bf16, rowsum -> 0 ----
__global__ __launch_bounds__(256) void cast_all(
    const float* __restrict__ x, const float* __restrict__ wq,
    const float* __restrict__ wk, const float* __restrict__ wv,
    const float* __restrict__ wo, unsigned short* __restrict__ xb,
    unsigned short* __restrict__ wqkvb, unsigned short* __restrict__ wob,
    float* __restrict__ rowsum) {
  const int NX4 = (int)((long long)BB * SS * HD / 4);
  const int W4 = HD * HD / 4;
  const int RS4 = BB * SS / 4;
  const int TOT = NX4 + 4 * W4 + RS4;
  int idx = blockIdx.x * blockDim.x + threadIdx.x;
  const int stride = gridDim.x * blockDim.x;
  for (int u = idx; u < TOT; u += stride) {
    if (u >= NX4 + 4 * W4) {
      *reinterpret_cast<float4*>(rowsum + (u - NX4 - 4 * W4) * 4) =
          make_float4(0.f, 0.f, 0.f, 0.f);
      continue;
    }
    const float* src;
    unsigned short* dst;
    int off;
    if (u < NX4) {
      src = x; dst = xb; off = u;
    } else {
      const int v = u - NX4;
      const int seg = v >> 18;
      off = v & (W4 - 1);
      if (seg == 0) { src = wq; dst = wqkvb; }
      else if (seg == 1) { src = wk; dst = wqkvb + HD * HD; }
      else if (seg == 2) { src = wv; dst = wqkvb + 2 * HD * HD; }
      else { src = wo; dst = wob; }
    }
    float4 f = *reinterpret_cast<const float4*>(src + off * 4);
    ushort4 o;
    o.x = f2bf(f.x); o.y = f2bf(f.y); o.z = f2bf(f.z); o.w = f2bf(f.w);
    *reinterpret_cast<ushort4*>(dst + off * 4) = o;
  }
}

extern "C" void kernel_launch(void* const* d_in, const int* in_sizes, int n_in,
                              void* d_out, int out_size, void* d_ws, size_t ws_size,
                              hipStream_t stream) {
  const float* x = (const float*)d_in[0];
  const int* amask = (const int*)d_in[1];
  const float* wq = (const float*)d_in[2];
  const float* bq = (const float*)d_in[3];
  const float* wk = (const float*)d_in[4];
  const float* bk = (const float*)d_in[5];
  const float* wv = (const float*)d_in[6];
  const float* bv = (const float*)d_in[7];
  const float* wo = (const float*)d_in[8];
  const float* bo = (const float*)d_in[9];
  float* out = (float*)d_out;

  const long long NX = (long long)BB * SS * HD;
  char* p = (char*)d_ws;
  unsigned short* xb = (unsigned short*)p;     p += NX * 2;
  unsigned short* wqkvb = (unsigned short*)p;  p += 3LL * HD * HD * 2;
  unsigned short* wob = (unsigned short*)p;    p += (long long)HD * HD * 2;
  unsigned short* Qb = (unsigned short*)p;     p += NX * 2;
  unsigned short* Kb = (unsigned short*)p;     p += NX * 2;
  unsigned short* Vtb = (unsigned short*)p;    p += NX * 2;  // [b][d][s]
  unsigned short* Sb = (unsigned short*)p;     p += (long long)BB * SS * SS * 2;
  float* rowsum = (float*)p;                   p += (long long)BB * SS * 4;
  unsigned short* AOb = xb;  // alias: x dead after qkv

  cast_all<<<dim3(2048), 256, 0, stream>>>(x, wq, wk, wv, wo, xb, wqkvb, wob,
                                           rowsum);

  qkv_kernel<<<dim3(1536), 512, 0, stream>>>(xb, wqkvb, bq, bk, bv, Qb, Kb,
                                             Vtb);

  scores_kernel<<<dim3(576), 512, 0, stream>>>(Qb, Kb, amask, Sb, rowsum);
  pv_kernel<<<dim3(512), 512, 0, stream>>>(Sb, Vtb, rowsum, AOb);

  oproj_kernel<<<dim3(512), 512, 0, stream>>>(AOb, wob, bo, out);
}

// Round 13
// 327.552 us; speedup vs baseline: 1.0910x; 1.0341x over previous
//
#include <hip/hip_runtime.h>
#include <hip/hip_bf16.h>

// SingleHeadCausalSelfAttention B=8 S=2048 H=1024 causal.
// R13 = R9 (best, 327us) with sched_barrier(0) removed from VM waits.
// Rule #18 requires the fence only after lgkmcnt(0) before register-MFMA;
// VM waits followed by memory ops are ordered by the "memory" clobber.
// m141: order-pinning the compiler's interleave is a measured regression
// mechanism -- this un-pins 3+ points per K-iteration.

typedef __bf16 bf16x8 __attribute__((ext_vector_type(8)));
typedef float f32x4 __attribute__((ext_vector_type(4)));

static constexpr int HD = 1024;
static constexpr int BB = 8;
static constexpr int SS = 2048;
static constexpr long long SH = (long long)SS * HD;

__device__ __forceinline__ unsigned short f2bf(float f) {
  unsigned u = __builtin_bit_cast(unsigned, f);
  return (unsigned short)((u + 0x7FFFu + ((u >> 16) & 1u)) >> 16);
}
__device__ __forceinline__ f32x4 mfma16(bf16x8 a, bf16x8 b, f32x4 c) {
  return __builtin_amdgcn_mfma_f32_16x16x32_bf16(a, b, c, 0, 0, 0);
}
__device__ __forceinline__ void gload_lds16(const void* g, void* l) {
  __builtin_amdgcn_global_load_lds(
      (const __attribute__((address_space(1))) void*)g,
      (__attribute__((address_space(3))) void*)l, 16, 0, 0);
}

// lgkm wait before register-MFMA needs the sched_barrier fence (rule #18).
#define WAIT_LGKM0() do { asm volatile("s_waitcnt lgkmcnt(0)" ::: "memory"); \
  __builtin_amdgcn_sched_barrier(0); } while (0)
// VM waits are followed by memory ops (ds_read/global_load_lds) which the
// "memory" clobber already orders -- no sched_barrier (m141: pinning hurts).
#define WAIT_VM(n) do { asm volatile("s_waitcnt vmcnt(" #n ")" ::: "memory"); \
} while (0)

// swizzled LDS read: logical (row, colbyte) -> byte ^ ((row&7)<<4)
__device__ __forceinline__ bf16x8 read_frag(const unsigned short* tile, int row,
                                            int colb) {
  int byte = row * 128 + colb;
  byte ^= (row & 7) << 4;
  return *reinterpret_cast<const bf16x8*>(
      reinterpret_cast<const char*>(tile) + byte);
}

// stage one half-tile (128 rows x 64 cols bf16); source cols pre-swizzled.
__device__ __forceinline__ void stage_half(const unsigned short* pM,
                                           long long ld, long long kt,
                                           unsigned short* tile, int h,
                                           int wid) {
  const unsigned short* s = pM + (long long)(h * 128) * ld + kt;
  gload_lds16(s, tile + h * 8192 + wid * 512);
  gload_lds16(s + 64 * ld, tile + h * 8192 + 4096 + wid * 512);
}

template <int MT, int Q>
__device__ __forceinline__ void ds_a(const unsigned short* At, int rA, int cb,
                                     bf16x8 af[2][2]) {
  constexpr int FPP = MT / 4;
#pragma unroll
  for (int f = 0; f < FPP; ++f) {
    af[f][0] = read_frag(At, rA + (FPP * Q + f) * 16, cb);
    af[f][1] = read_frag(At, rA + (FPP * Q + f) * 16, 64 + cb);
  }
}
__device__ __forceinline__ void ds_b(const unsigned short* Bt, int rB, int cb,
                                     bf16x8 B[4][2]) {
#pragma unroll
  for (int ni = 0; ni < 4; ++ni) {
    B[ni][0] = read_frag(Bt, rB + ni * 16, cb);
    B[ni][1] = read_frag(Bt, rB + ni * 16, 64 + cb);
  }
}
template <int MT, int Q>
__device__ __forceinline__ void mfma_q(const bf16x8 af[2][2],
                                       const bf16x8 B[4][2],
                                       f32x4 (&acc)[MT][4]) {
  constexpr int FPP = MT / 4;
#pragma unroll
  for (int f = 0; f < FPP; ++f)
#pragma unroll
    for (int ni = 0; ni < 4; ++ni) {
      acc[FPP * Q + f][ni] = mfma16(af[f][0], B[ni][0], acc[FPP * Q + f][ni]);
      acc[FPP * Q + f][ni] = mfma16(af[f][1], B[ni][1], acc[FPP * Q + f][ni]);
    }
}

#define PH_TAIL(QN, BRG) do { \
  __builtin_amdgcn_s_barrier(); \
  WAIT_LGKM0(); \
  __builtin_amdgcn_s_setprio(1); \
  mfma_q<MT, QN>(af, BRG, acc); \
  __builtin_amdgcn_s_setprio(0); \
  __builtin_amdgcn_s_barrier(); \
} while (0)

// MT*32-row x 256-col output tile over K = NT*64 (NT even, >=2).
// Wait constants verified by retire-set trace (R9/R13 audit).
template <int MT>
__device__ __forceinline__ void run_tile(
    const unsigned short* pA, const unsigned short* pB, long long lda,
    long long ldb, int NT, unsigned short* As0, unsigned short* As1,
    unsigned short* Bs0, unsigned short* Bs1, int wid, int rA, int rB, int cb,
    f32x4 (&acc)[MT][4]) {
  bf16x8 BA[4][2], BB[4][2], af[2][2];
  stage_half(pA, lda, 0, As0, 0, wid);
  if constexpr (MT == 8) stage_half(pA, lda, 0, As0, 1, wid);
  stage_half(pB, ldb, 0, Bs0, 0, wid);
  stage_half(pB, ldb, 0, Bs0, 1, wid);
  stage_half(pB, ldb, 64, Bs1, 0, wid);
  stage_half(pB, ldb, 64, Bs1, 1, wid);
  WAIT_VM(4);  // retire A0,B0; leave B1 (4 loads)
  __builtin_amdgcn_s_barrier();
  ds_b(Bs0, rB, cb, BA);
  WAIT_LGKM0();
  __builtin_amdgcn_s_barrier();

  const int NITER = NT / 2 - 1;
  for (int i = 0; i < NITER; ++i) {
    const long long kA1 = (long long)(2 * i + 1) * 64;
    const long long kN2 = (long long)(2 * i + 2) * 64;
    const long long kB3 = (long long)(2 * i + 3) * 64;
    WAIT_VM(4);  // retire P5/P6-prev -> As0 ready
    ds_a<MT, 0>(As0, rA, cb, af); stage_half(pA, lda, kA1, As1, 0, wid); PH_TAIL(0, BA);
    ds_a<MT, 1>(As0, rA, cb, af);
    if constexpr (MT == 8) stage_half(pA, lda, kA1, As1, 1, wid);
    PH_TAIL(1, BA);
    ds_a<MT, 2>(As0, rA, cb, af); stage_half(pB, ldb, kN2, Bs0, 0, wid); PH_TAIL(2, BA);
    WAIT_VM(2);  // retire B-odd (Bs1) AND P1/P2 (As1) -> both ready
    ds_a<MT, 3>(As0, rA, cb, af); ds_b(Bs1, rB, cb, BB);
    stage_half(pB, ldb, kN2, Bs0, 1, wid); PH_TAIL(3, BA);
    ds_a<MT, 0>(As1, rA, cb, af); stage_half(pA, lda, kN2, As0, 0, wid); PH_TAIL(0, BB);
    ds_a<MT, 1>(As1, rA, cb, af);
    if constexpr (MT == 8) stage_half(pA, lda, kN2, As0, 1, wid);
    PH_TAIL(1, BB);
    ds_a<MT, 2>(As1, rA, cb, af); stage_half(pB, ldb, kB3, Bs1, 0, wid); PH_TAIL(2, BB);
    if constexpr (MT == 8) WAIT_VM(6); else WAIT_VM(4);  // retire P3/P4 -> Bs0-next
    ds_a<MT, 3>(As1, rA, cb, af); ds_b(Bs0, rB, cb, BA);
    stage_half(pB, ldb, kB3, Bs1, 1, wid); PH_TAIL(3, BB);
  }
  // drain: tile NT-2 (buf0, BA ready) and NT-1 (B in Bs1; A staged now)
  const long long kL = (long long)(NT - 1) * 64;
  WAIT_VM(4);  // retire P5/P6 -> As0 = A(NT-2) ready
  ds_a<MT, 0>(As0, rA, cb, af); stage_half(pA, lda, kL, As1, 0, wid); PH_TAIL(0, BA);
  ds_a<MT, 1>(As0, rA, cb, af);
  if constexpr (MT == 8) stage_half(pA, lda, kL, As1, 1, wid);
  PH_TAIL(1, BA);
  ds_a<MT, 2>(As0, rA, cb, af); PH_TAIL(2, BA);
  if constexpr (MT == 8) WAIT_VM(4); else WAIT_VM(2);  // retire P7/P8 -> Bs1
  ds_a<MT, 3>(As0, rA, cb, af); ds_b(Bs1, rB, cb, BB); PH_TAIL(3, BA);
  WAIT_VM(0);  // retire A-last stages -> As1
  ds_a<MT, 0>(As1, rA, cb, af); PH_TAIL(0, BB);
  ds_a<MT, 1>(As1, rA, cb, af); PH_TAIL(1, BB);
  ds_a<MT, 2>(As1, rA, cb, af); PH_TAIL(2, BB);
  ds_a<MT, 3>(As1, rA, cb, af); PH_TAIL(3, BB);
}

struct TC {
  int wid, lane, wm, wn, rA, rB, cb, rr, ccl, rowt, colg;
};
template <int MT>
__device__ __forceinline__ TC tc_setup() {
  TC t;
  const int tid = threadIdx.x;
  t.wid = tid >> 6;
  t.lane = tid & 63;
  t.wm = t.wid >> 2;
  t.wn = t.wid & 3;
  const int l16 = t.lane & 15;
  t.rA = t.wm * (MT * 16) + l16;
  t.rB = t.wn * 64 + l16;
  t.cb = (t.lane >> 4) * 16;
  t.rr = (t.lane >> 4) * 4;
  t.ccl = l16;
  t.rowt = tid >> 3;
  t.colg = (((tid & 7) ^ ((tid >> 3) & 7)) * 8);  // inverse of read swizzle
  return t;
}

#define SHARED_TILES8() \
  __shared__ __align__(16) unsigned short As0[16384], As1[16384]; \
  __shared__ __align__(16) unsigned short Bs0[16384], Bs1[16384]
#define SHARED_TILES4() \
  __shared__ __align__(16) unsigned short As0[8192], As1[8192]; \
  __shared__ __align__(16) unsigned short Bs0[16384], Bs1[16384]

// ---- QK fused projection: C[16384][2048] -> Q | K ----
__global__ __launch_bounds__(512, 2) void qk_kernel(
    const unsigned short* __restrict__ X, const unsigned short* __restrict__ W,
    const float* __restrict__ bq, const float* __restrict__ bk,
    unsigned short* __restrict__ Q, unsigned short* __restrict__ K) {
  SHARED_TILES8();
  const int lin = blockIdx.y * 8 + blockIdx.x;
  const int swz = (lin & 7) * 64 + (lin >> 3);
  const int m0 = (swz >> 3) * 256, n0 = (swz & 7) * 256;
  TC t = tc_setup<8>();
  const unsigned short* pA = X + (long long)(m0 + t.rowt) * HD + t.colg;
  const unsigned short* pB = W + (long long)(n0 + t.rowt) * HD + t.colg;
  f32x4 acc[8][4] = {};
  run_tile<8>(pA, pB, HD, HD, 16, As0, As1, Bs0, Bs1, t.wid, t.rA, t.rB, t.cb, acc);
#pragma unroll
  for (int mi = 0; mi < 8; ++mi)
#pragma unroll
    for (int ni = 0; ni < 4; ++ni) {
      const int gn = n0 + t.wn * 64 + ni * 16 + t.ccl;
      const float bias = (gn < 1024) ? bq[gn] : bk[gn - 1024];
      unsigned short* dst = (gn < 1024) ? (Q + gn) : (K + gn - 1024);
#pragma unroll
      for (int j = 0; j < 4; ++j) {
        const int gm = m0 + t.wm * 128 + mi * 16 + t.rr + j;
        dst[(long long)gm * HD] = f2bf(acc[mi][ni][j] + bias);
      }
    }
}

// ---- fused middle: blocks 0..255 = V^T GEMM; blocks 256..543 = scores ----
__global__ __launch_bounds__(512, 2) void mid_kernel(
    const unsigned short* __restrict__ Wv, const unsigned short* __restrict__ X,
    const float* __restrict__ bv, unsigned short* __restrict__ Vt,
    const unsigned short* __restrict__ Q, const unsigned short* __restrict__ Km,
    const int* __restrict__ mask, unsigned short* __restrict__ S,
    float* __restrict__ rowsum) {
  SHARED_TILES8();
  TC t = tc_setup<8>();
  if (blockIdx.x < 256) {
    // V^T: A=Wv[1024][1024], B=x[16384][1024]; C[d][gs] -> Vt[b][d][s]
    const int lin = blockIdx.x;
    const int swz = (lin & 7) * 32 + (lin >> 3);
    const int m0 = (swz & 3) * 256, n0 = (swz >> 2) * 256;
    const unsigned short* pA = Wv + (long long)(m0 + t.rowt) * HD + t.colg;
    const unsigned short* pB = X + (long long)(n0 + t.rowt) * HD + t.colg;
    f32x4 acc[8][4] = {};
    run_tile<8>(pA, pB, HD, HD, 16, As0, As1, Bs0, Bs1, t.wid, t.rA, t.rB,
                t.cb, acc);
#pragma unroll
    for (int mi = 0; mi < 8; ++mi)
#pragma unroll
      for (int ni = 0; ni < 4; ++ni) {
        const int gn = n0 + t.wn * 64 + ni * 16 + t.ccl;  // gs
        const long long base = (long long)(gn >> 11) * SH + (gn & 2047);
#pragma unroll
        for (int j = 0; j < 4; ++j) {
          const int gm = m0 + t.wm * 128 + mi * 16 + t.rr + j;  // d
          Vt[base + (long long)gm * SS] = f2bf(acc[mi][ni][j] + bv[gm]);
        }
      }
  } else {
    // scores: 256^2 causal triangle tile; exp + LDS-reduced rowsum
    const int s = blockIdx.x - 256;    // 0..287
    const long long b = s & 7;         // batch -> XCD pin
    int tt = s >> 3;                   // 0..35 triangle index
    int ii = 0, base = 0;
    while (tt >= base + ii + 1) { base += ii + 1; ++ii; }
    const int jj = tt - base;
    const int m0 = ii * 256, n0 = jj * 256;
    const unsigned short* pA =
        Q + b * SH + (long long)(m0 + t.rowt) * HD + t.colg;
    const unsigned short* pB =
        Km + b * SH + (long long)(n0 + t.rowt) * HD + t.colg;
    f32x4 acc[8][4] = {};
    run_tile<8>(pA, pB, HD, HD, 16, As0, As1, Bs0, Bs1, t.wid, t.rA, t.rB,
                t.cb, acc);
    unsigned short* Sb = S + b * (long long)SS * SS;
    const int* mb = mask + b * SS;
    float* rs = rowsum + b * SS;
    float* rsl = reinterpret_cast<float*>(As0);  // 4KB scratch, LDS dead
#pragma unroll
    for (int mi = 0; mi < 8; ++mi)
#pragma unroll
      for (int j = 0; j < 4; ++j) {
        const int gm = m0 + t.wm * 128 + mi * 16 + t.rr + j;
        float rsum = 0.0f;
#pragma unroll
        for (int ni = 0; ni < 4; ++ni) {
          const int gn = n0 + t.wn * 64 + ni * 16 + t.ccl;
          const bool dead = (gn > gm) || (mb[gn] == 0);
          const float pv = dead ? 0.0f : __expf(acc[mi][ni][j] * 0.03125f);
          Sb[(long long)gm * SS + gn] = f2bf(pv);
          rsum += pv;
        }
#pragma unroll
        for (int o = 1; o < 16; o <<= 1) rsum += __shfl_xor(rsum, o);
        if (t.ccl == 0)
          rsl[t.wn * 256 + (t.wm * 128 + mi * 16 + t.rr + j)] = rsum;
      }
    __syncthreads();
    const int tid = threadIdx.x;
    if (tid < 256) {
      const float v =
          rsl[tid] + rsl[256 + tid] + rsl[512 + tid] + rsl[768 + tid];
      atomicAdd(&rs[m0 + tid], v);
    }
  }
}

// ---- PV: paired m-tiles p/(15-p) (128 rows), uniform 34 K-tiles; /rowsum ----
__global__ __launch_bounds__(512, 2) void pv_kernel(
    const unsigned short* __restrict__ S, const unsigned short* __restrict__ Vt,
    const float* __restrict__ rowsum, unsigned short* __restrict__ AO) {
  SHARED_TILES4();
  const int bid = blockIdx.x;
  const long long b = bid & 7;       // batch -> XCD pin
  const int r = bid >> 3;            // 0..31
  const int p = r & 7;
  const int n0 = (r >> 3) * 256;
  const unsigned short* Sb = S + b * (long long)SS * SS;
  const unsigned short* Vb = Vt + b * SH;
  const float* rs = rowsum + b * SS;
  TC t = tc_setup<4>();

  for (int pass = 0; pass < 2; ++pass) {
    const int mi0 = pass ? 15 - p : p;
    const int m0 = mi0 * 128;
    const int NT = 2 * (mi0 + 1);
    const unsigned short* pA = Sb + (long long)(m0 + t.rowt) * SS + t.colg;
    const unsigned short* pB = Vb + (long long)(n0 + t.rowt) * SS + t.colg;
    f32x4 acc[4][4] = {};
    run_tile<4>(pA, pB, SS, SS, NT, As0, As1, Bs0, Bs1, t.wid, t.rA, t.rB,
                t.cb, acc);
#pragma unroll
    for (int mi = 0; mi < 4; ++mi)
#pragma unroll
      for (int j = 0; j < 4; ++j) {
        const int gm = m0 + t.wm * 64 + mi * 16 + t.rr + j;
        const float inv = 1.0f / rs[gm];
#pragma unroll
        for (int ni = 0; ni < 4; ++ni) {
          const int gn = n0 + t.wn * 64 + ni * 16 + t.ccl;
          AO[(b * SS + gm) * (long long)HD + gn] = f2bf(acc[mi][ni][j] * inv);
        }
      }
  }
}

// ---- output projection: f32 out ----
__global__ __launch_bounds__(512, 2) void oproj_kernel(
    const unsigned short* __restrict__ AO, const unsigned short* __restrict__ W,
    const float* __restrict__ bo, float* __restrict__ out) {
  SHARED_TILES8();
  const int lin = blockIdx.x;
  const int swz = (lin & 7) * 32 + (lin >> 3);
  const int n0 = (swz & 3) * 256, m0 = (swz >> 2) * 256;
  TC t = tc_setup<8>();
  const unsigned short* pA = AO + (long long)(m0 + t.rowt) * HD + t.colg;
  const unsigned short* pB = W + (long long)(n0 + t.rowt) * HD + t.colg;
  f32x4 acc[8][4] = {};
  run_tile<8>(pA, pB, HD, HD, 16, As0, As1, Bs0, Bs1, t.wid, t.rA, t.rB, t.cb, acc);
#pragma unroll
  for (int mi = 0; mi < 8; ++mi)
#pragma unroll
    for (int ni = 0; ni < 4; ++ni) {
      const int gn = n0 + t.wn * 64 + ni * 16 + t.ccl;
      const float bias = bo[gn];
#pragma unroll
      for (int j = 0; j < 4; ++j) {
        const int gm = m0 + t.wm * 128 + mi * 16 + t.rr + j;
        out[(long long)gm * HD + gn] = acc[mi][ni][j] + bias;
      }
    }
}

// ---- single cast dispatch: x + 4 weights -> bf16, rowsum -> 0 ----
__global__ __launch_bounds__(256) void cast_all(
    const float* __restrict__ x, const float* __restrict__ wq,
    const float* __restrict__ wk, const float* __restrict__ wv,
    const float* __restrict__ wo, unsigned short* __restrict__ xb,
    unsigned short* __restrict__ wqkb, unsigned short* __restrict__ wvb,
    unsigned short* __restrict__ wob, float* __restrict__ rowsum) {
  const int NX4 = (int)((long long)BB * SS * HD / 4);  // 4194304
  const int W4 = HD * HD / 4;                          // 262144
  const int RS4 = BB * SS / 4;                         // 4096
  const int TOT = NX4 + 4 * W4 + RS4;
  int idx = blockIdx.x * blockDim.x + threadIdx.x;
  const int stride = gridDim.x * blockDim.x;
  for (int u = idx; u < TOT; u += stride) {
    if (u >= NX4 + 4 * W4) {
      *reinterpret_cast<float4*>(rowsum + (u - NX4 - 4 * W4) * 4) =
          make_float4(0.f, 0.f, 0.f, 0.f);
      continue;
    }
    const float* src;
    unsigned short* dst;
    int off;
    if (u < NX4) {
      src = x; dst = xb; off = u;
    } else {
      const int v = u - NX4;
      const int seg = v >> 18;
      off = v & (W4 - 1);
      if (seg == 0) { src = wq; dst = wqkb; }
      else if (seg == 1) { src = wk; dst = wqkb + HD * HD; }
      else if (seg == 2) { src = wv; dst = wvb; }
      else { src = wo; dst = wob; }
    }
    float4 f = *reinterpret_cast<const float4*>(src + off * 4);
    ushort4 o;
    o.x = f2bf(f.x); o.y = f2bf(f.y); o.z = f2bf(f.z); o.w = f2bf(f.w);
    *reinterpret_cast<ushort4*>(dst + off * 4) = o;
  }
}

extern "C" void kernel_launch(void* const* d_in, const int* in_sizes, int n_in,
                              void* d_out, int out_size, void* d_ws, size_t ws_size,
                              hipStream_t stream) {
  const float* x = (const float*)d_in[0];
  const int* amask = (const int*)d_in[1];
  const float* wq = (const float*)d_in[2];
  const float* bq = (const float*)d_in[3];
  const float* wk = (const float*)d_in[4];
  const float* bk = (const float*)d_in[5];
  const float* wv = (const float*)d_in[6];
  const float* bv = (const float*)d_in[7];
  const float* wo = (const float*)d_in[8];
  const float* bo = (const float*)d_in[9];
  float* out = (float*)d_out;

  const long long NX = (long long)BB * SS * HD;
  char* p = (char*)d_ws;
  unsigned short* xb = (unsigned short*)p;    p += NX * 2;
  unsigned short* wqkb = (unsigned short*)p;  p += 2LL * HD * HD * 2;
  unsigned short* wvb = (unsigned short*)p;   p += (long long)HD * HD * 2;
  unsigned short* wob = (unsigned short*)p;   p += (long long)HD * HD * 2;
  unsigned short* Qb = (unsigned short*)p;    p += NX * 2;
  unsigned short* Kb = (unsigned short*)p;    p += NX * 2;
  unsigned short* Vtb = (unsigned short*)p;   p += NX * 2;  // [b][d][s]
  unsigned short* Sb = (unsigned short*)p;    p += (long long)BB * SS * SS * 2;
  float* rowsum = (float*)p;                  p += (long long)BB * SS * 4;
  unsigned short* AOb = xb;  // alias: x dead after QK + mid projections

  cast_all<<<dim3(2048), 256, 0, stream>>>(x, wq, wk, wv, wo, xb, wqkb, wvb,
                                           wob, rowsum);

  qk_kernel<<<dim3(8, 64), 512, 0, stream>>>(xb, wqkb, bq, bk, Qb, Kb);

  mid_kernel<<<dim3(544), 512, 0, stream>>>(wvb, xb, bv, Vtb, Qb, Kb, amask,
                                            Sb, rowsum);

  pv_kernel<<<dim3(256), 512, 0, stream>>>(Sb, Vtb, rowsum, AOb);

  oproj_kernel<<<dim3(256), 512, 0, stream>>>(AOb, wob, bo, out);
}

// Round 14
// 323.790 us; speedup vs baseline: 1.1037x; 1.0116x over previous
//
#include <hip/hip_runtime.h>
#include <hip/hip_bf16.h>

// SingleHeadCausalSelfAttention B=8 S=2048 H=1024 causal.
// R14 = R13 with the K-loop phase schedule rebalanced:
//  - ds_b split lo/hi: BB-lo@P4, BB-hi@P5, BA-lo@P8, BA-hi@P1 (prologue reads
//    BA-lo only). Max ds_reads/phase 12 -> 8 (the P4/P8 LDS spike was ~770
//    extra cyc/phase: all 8 waves drain 96 reads before MFMA).
//  - waits consolidated: vm(2) at P4-start and P8-start only (retire-set
//    traced for MT8/MT4, prologue, drain, NT=2). Loop-top wait dropped.

typedef __bf16 bf16x8 __attribute__((ext_vector_type(8)));
typedef float f32x4 __attribute__((ext_vector_type(4)));

static constexpr int HD = 1024;
static constexpr int BB = 8;
static constexpr int SS = 2048;
static constexpr long long SH = (long long)SS * HD;

__device__ __forceinline__ unsigned short f2bf(float f) {
  unsigned u = __builtin_bit_cast(unsigned, f);
  return (unsigned short)((u + 0x7FFFu + ((u >> 16) & 1u)) >> 16);
}
__device__ __forceinline__ f32x4 mfma16(bf16x8 a, bf16x8 b, f32x4 c) {
  return __builtin_amdgcn_mfma_f32_16x16x32_bf16(a, b, c, 0, 0, 0);
}
__device__ __forceinline__ void gload_lds16(const void* g, void* l) {
  __builtin_amdgcn_global_load_lds(
      (const __attribute__((address_space(1))) void*)g,
      (__attribute__((address_space(3))) void*)l, 16, 0, 0);
}

#define WAIT_LGKM0() do { asm volatile("s_waitcnt lgkmcnt(0)" ::: "memory"); \
  __builtin_amdgcn_sched_barrier(0); } while (0)
#define WAIT_VM(n) do { asm volatile("s_waitcnt vmcnt(" #n ")" ::: "memory"); \
} while (0)

// swizzled LDS read: logical (row, colbyte) -> byte ^ ((row&7)<<4)
__device__ __forceinline__ bf16x8 read_frag(const unsigned short* tile, int row,
                                            int colb) {
  int byte = row * 128 + colb;
  byte ^= (row & 7) << 4;
  return *reinterpret_cast<const bf16x8*>(
      reinterpret_cast<const char*>(tile) + byte);
}

// stage one half-tile (128 rows x 64 cols bf16); source cols pre-swizzled.
__device__ __forceinline__ void stage_half(const unsigned short* pM,
                                           long long ld, long long kt,
                                           unsigned short* tile, int h,
                                           int wid) {
  const unsigned short* s = pM + (long long)(h * 128) * ld + kt;
  gload_lds16(s, tile + h * 8192 + wid * 512);
  gload_lds16(s + 64 * ld, tile + h * 8192 + 4096 + wid * 512);
}

template <int MT, int Q>
__device__ __forceinline__ void ds_a(const unsigned short* At, int rA, int cb,
                                     bf16x8 af[2][2]) {
  constexpr int FPP = MT / 4;
#pragma unroll
  for (int f = 0; f < FPP; ++f) {
    af[f][0] = read_frag(At, rA + (FPP * Q + f) * 16, cb);
    af[f][1] = read_frag(At, rA + (FPP * Q + f) * 16, 64 + cb);
  }
}
// HALF=0: ni 0,1 ; HALF=1: ni 2,3  (4 x ds_read_b128 each)
template <int HALF>
__device__ __forceinline__ void ds_b_half(const unsigned short* Bt, int rB,
                                          int cb, bf16x8 B[4][2]) {
#pragma unroll
  for (int ni = 2 * HALF; ni < 2 * HALF + 2; ++ni) {
    B[ni][0] = read_frag(Bt, rB + ni * 16, cb);
    B[ni][1] = read_frag(Bt, rB + ni * 16, 64 + cb);
  }
}
template <int MT, int Q>
__device__ __forceinline__ void mfma_q(const bf16x8 af[2][2],
                                       const bf16x8 B[4][2],
                                       f32x4 (&acc)[MT][4]) {
  constexpr int FPP = MT / 4;
#pragma unroll
  for (int f = 0; f < FPP; ++f)
#pragma unroll
    for (int ni = 0; ni < 4; ++ni) {
      acc[FPP * Q + f][ni] = mfma16(af[f][0], B[ni][0], acc[FPP * Q + f][ni]);
      acc[FPP * Q + f][ni] = mfma16(af[f][1], B[ni][1], acc[FPP * Q + f][ni]);
    }
}

#define PH_TAIL(QN, BRG) do { \
  __builtin_amdgcn_s_barrier(); \
  WAIT_LGKM0(); \
  __builtin_amdgcn_s_setprio(1); \
  mfma_q<MT, QN>(af, BRG, acc); \
  __builtin_amdgcn_s_setprio(0); \
  __builtin_amdgcn_s_barrier(); \
} while (0)

// MT*32-row x 256-col output tile over K = NT*64 (NT even, >=2).
// Stage slots (iter i): P1:As1<-A(2i+1) [P2:h1 MT8], P3/P4:Bs0<-B(2i+2),
// P5:As0<-A(2i+2) [P6:h1 MT8], P7/P8:Bs1<-B(2i+3).
// Waits: vm(2) at P4-start (retires prev Bs1 + As1) and P8-start (retires
// Bs0 + As0). Steady-state leftover after each wait = newest 2 loads.
template <int MT>
__device__ __forceinline__ void run_tile(
    const unsigned short* pA, const unsigned short* pB, long long lda,
    long long ldb, int NT, unsigned short* As0, unsigned short* As1,
    unsigned short* Bs0, unsigned short* Bs1, int wid, int rA, int rB, int cb,
    f32x4 (&acc)[MT][4]) {
  bf16x8 BA[4][2], BBr[4][2], af[2][2];
  stage_half(pA, lda, 0, As0, 0, wid);
  if constexpr (MT == 8) stage_half(pA, lda, 0, As0, 1, wid);
  stage_half(pB, ldb, 0, Bs0, 0, wid);
  stage_half(pB, ldb, 0, Bs0, 1, wid);
  stage_half(pB, ldb, 64, Bs1, 0, wid);
  stage_half(pB, ldb, 64, Bs1, 1, wid);
  WAIT_VM(4);  // retire A0,B0; leave B1 (4 loads)
  __builtin_amdgcn_s_barrier();
  ds_b_half<0>(Bs0, rB, cb, BA);  // BA-lo; BA-hi read at P1
  WAIT_LGKM0();
  __builtin_amdgcn_s_barrier();

  const int NITER = NT / 2 - 1;
  for (int i = 0; i < NITER; ++i) {
    const long long kA1 = (long long)(2 * i + 1) * 64;
    const long long kN2 = (long long)(2 * i + 2) * 64;
    const long long kB3 = (long long)(2 * i + 3) * 64;
    // P1
    ds_b_half<1>(Bs0, rB, cb, BA);
    ds_a<MT, 0>(As0, rA, cb, af); stage_half(pA, lda, kA1, As1, 0, wid);
    PH_TAIL(0, BA);
    // P2
    ds_a<MT, 1>(As0, rA, cb, af);
    if constexpr (MT == 8) stage_half(pA, lda, kA1, As1, 1, wid);
    PH_TAIL(1, BA);
    // P3
    ds_a<MT, 2>(As0, rA, cb, af); stage_half(pB, ldb, kN2, Bs0, 0, wid);
    PH_TAIL(2, BA);
    // P4
    WAIT_VM(2);  // retire prev Bs1 (B 2i+1) + As1 (P1/P2); leave P3
    ds_a<MT, 3>(As0, rA, cb, af); ds_b_half<0>(Bs1, rB, cb, BBr);
    stage_half(pB, ldb, kN2, Bs0, 1, wid);
    PH_TAIL(3, BA);
    // P5
    ds_b_half<1>(Bs1, rB, cb, BBr);
    ds_a<MT, 0>(As1, rA, cb, af); stage_half(pA, lda, kN2, As0, 0, wid);
    PH_TAIL(0, BBr);
    // P6
    ds_a<MT, 1>(As1, rA, cb, af);
    if constexpr (MT == 8) stage_half(pA, lda, kN2, As0, 1, wid);
    PH_TAIL(1, BBr);
    // P7
    ds_a<MT, 2>(As1, rA, cb, af); stage_half(pB, ldb, kB3, Bs1, 0, wid);
    PH_TAIL(2, BBr);
    // P8
    WAIT_VM(2);  // retire Bs0 (B 2i+2) + As0 (A 2i+2); leave P7
    ds_a<MT, 3>(As1, rA, cb, af); ds_b_half<0>(Bs0, rB, cb, BA);
    stage_half(pB, ldb, kB3, Bs1, 1, wid);
    PH_TAIL(3, BBr);
  }
  // drain: tile NT-2 (As0, BA) then NT-1 (As1 staged now, Bs1 in flight)
  const long long kL = (long long)(NT - 1) * 64;
  // D1
  ds_b_half<1>(Bs0, rB, cb, BA);
  ds_a<MT, 0>(As0, rA, cb, af); stage_half(pA, lda, kL, As1, 0, wid);
  PH_TAIL(0, BA);
  // D2
  ds_a<MT, 1>(As0, rA, cb, af);
  if constexpr (MT == 8) stage_half(pA, lda, kL, As1, 1, wid);
  PH_TAIL(1, BA);
  // D3
  ds_a<MT, 2>(As0, rA, cb, af); PH_TAIL(2, BA);
  // D4: retire Bs1 (B NT-1); leave As1 stages
  if constexpr (MT == 8) { WAIT_VM(4); } else { WAIT_VM(2); }
  ds_a<MT, 3>(As0, rA, cb, af); ds_b_half<0>(Bs1, rB, cb, BBr);
  PH_TAIL(3, BA);
  // D5: retire As1 stages
  WAIT_VM(0);
  ds_b_half<1>(Bs1, rB, cb, BBr);
  ds_a<MT, 0>(As1, rA, cb, af); PH_TAIL(0, BBr);
  ds_a<MT, 1>(As1, rA, cb, af); PH_TAIL(1, BBr);
  ds_a<MT, 2>(As1, rA, cb, af); PH_TAIL(2, BBr);
  ds_a<MT, 3>(As1, rA, cb, af); PH_TAIL(3, BBr);
}

struct TC {
  int wid, lane, wm, wn, rA, rB, cb, rr, ccl, rowt, colg;
};
template <int MT>
__device__ __forceinline__ TC tc_setup() {
  TC t;
  const int tid = threadIdx.x;
  t.wid = tid >> 6;
  t.lane = tid & 63;
  t.wm = t.wid >> 2;
  t.wn = t.wid & 3;
  const int l16 = t.lane & 15;
  t.rA = t.wm * (MT * 16) + l16;
  t.rB = t.wn * 64 + l16;
  t.cb = (t.lane >> 4) * 16;
  t.rr = (t.lane >> 4) * 4;
  t.ccl = l16;
  t.rowt = tid >> 3;
  t.colg = (((tid & 7) ^ ((tid >> 3) & 7)) * 8);  // inverse of read swizzle
  return t;
}

#define SHARED_TILES8() \
  __shared__ __align__(16) unsigned short As0[16384], As1[16384]; \
  __shared__ __align__(16) unsigned short Bs0[16384], Bs1[16384]
#define SHARED_TILES4() \
  __shared__ __align__(16) unsigned short As0[8192], As1[8192]; \
  __shared__ __align__(16) unsigned short Bs0[16384], Bs1[16384]

// ---- QK fused projection: C[16384][2048] -> Q | K ----
__global__ __launch_bounds__(512, 2) void qk_kernel(
    const unsigned short* __restrict__ X, const unsigned short* __restrict__ W,
    const float* __restrict__ bq, const float* __restrict__ bk,
    unsigned short* __restrict__ Q, unsigned short* __restrict__ K) {
  SHARED_TILES8();
  const int lin = blockIdx.y * 8 + blockIdx.x;
  const int swz = (lin & 7) * 64 + (lin >> 3);
  const int m0 = (swz >> 3) * 256, n0 = (swz & 7) * 256;
  TC t = tc_setup<8>();
  const unsigned short* pA = X + (long long)(m0 + t.rowt) * HD + t.colg;
  const unsigned short* pB = W + (long long)(n0 + t.rowt) * HD + t.colg;
  f32x4 acc[8][4] = {};
  run_tile<8>(pA, pB, HD, HD, 16, As0, As1, Bs0, Bs1, t.wid, t.rA, t.rB, t.cb, acc);
#pragma unroll
  for (int mi = 0; mi < 8; ++mi)
#pragma unroll
    for (int ni = 0; ni < 4; ++ni) {
      const int gn = n0 + t.wn * 64 + ni * 16 + t.ccl;
      const float bias = (gn < 1024) ? bq[gn] : bk[gn - 1024];
      unsigned short* dst = (gn < 1024) ? (Q + gn) : (K + gn - 1024);
#pragma unroll
      for (int j = 0; j < 4; ++j) {
        const int gm = m0 + t.wm * 128 + mi * 16 + t.rr + j;
        dst[(long long)gm * HD] = f2bf(acc[mi][ni][j] + bias);
      }
    }
}

// ---- fused middle: blocks 0..255 = V^T GEMM; blocks 256..543 = scores ----
__global__ __launch_bounds__(512, 2) void mid_kernel(
    const unsigned short* __restrict__ Wv, const unsigned short* __restrict__ X,
    const float* __restrict__ bv, unsigned short* __restrict__ Vt,
    const unsigned short* __restrict__ Q, const unsigned short* __restrict__ Km,
    const int* __restrict__ mask, unsigned short* __restrict__ S,
    float* __restrict__ rowsum) {
  SHARED_TILES8();
  TC t = tc_setup<8>();
  if (blockIdx.x < 256) {
    const int lin = blockIdx.x;
    const int swz = (lin & 7) * 32 + (lin >> 3);
    const int m0 = (swz & 3) * 256, n0 = (swz >> 2) * 256;
    const unsigned short* pA = Wv + (long long)(m0 + t.rowt) * HD + t.colg;
    const unsigned short* pB = X + (long long)(n0 + t.rowt) * HD + t.colg;
    f32x4 acc[8][4] = {};
    run_tile<8>(pA, pB, HD, HD, 16, As0, As1, Bs0, Bs1, t.wid, t.rA, t.rB,
                t.cb, acc);
#pragma unroll
    for (int mi = 0; mi < 8; ++mi)
#pragma unroll
      for (int ni = 0; ni < 4; ++ni) {
        const int gn = n0 + t.wn * 64 + ni * 16 + t.ccl;  // gs
        const long long base = (long long)(gn >> 11) * SH + (gn & 2047);
#pragma unroll
        for (int j = 0; j < 4; ++j) {
          const int gm = m0 + t.wm * 128 + mi * 16 + t.rr + j;  // d
          Vt[base + (long long)gm * SS] = f2bf(acc[mi][ni][j] + bv[gm]);
        }
      }
  } else {
    const int s = blockIdx.x - 256;    // 0..287
    const long long b = s & 7;         // batch -> XCD pin
    int tt = s >> 3;                   // 0..35 triangle index
    int ii = 0, base = 0;
    while (tt >= base + ii + 1) { base += ii + 1; ++ii; }
    const int jj = tt - base;
    const int m0 = ii * 256, n0 = jj * 256;
    const unsigned short* pA =
        Q + b * SH + (long long)(m0 + t.rowt) * HD + t.colg;
    const unsigned short* pB =
        Km + b * SH + (long long)(n0 + t.rowt) * HD + t.colg;
    f32x4 acc[8][4] = {};
    run_tile<8>(pA, pB, HD, HD, 16, As0, As1, Bs0, Bs1, t.wid, t.rA, t.rB,
                t.cb, acc);
    unsigned short* Sb = S + b * (long long)SS * SS;
    const int* mb = mask + b * SS;
    float* rs = rowsum + b * SS;
    float* rsl = reinterpret_cast<float*>(As0);  // 4KB scratch, LDS dead
#pragma unroll
    for (int mi = 0; mi < 8; ++mi)
#pragma unroll
      for (int j = 0; j < 4; ++j) {
        const int gm = m0 + t.wm * 128 + mi * 16 + t.rr + j;
        float rsum = 0.0f;
#pragma unroll
        for (int ni = 0; ni < 4; ++ni) {
          const int gn = n0 + t.wn * 64 + ni * 16 + t.ccl;
          const bool dead = (gn > gm) || (mb[gn] == 0);
          const float pv = dead ? 0.0f : __expf(acc[mi][ni][j] * 0.03125f);
          Sb[(long long)gm * SS + gn] = f2bf(pv);
          rsum += pv;
        }
#pragma unroll
        for (int o = 1; o < 16; o <<= 1) rsum += __shfl_xor(rsum, o);
        if (t.ccl == 0)
          rsl[t.wn * 256 + (t.wm * 128 + mi * 16 + t.rr + j)] = rsum;
      }
    __syncthreads();
    const int tid = threadIdx.x;
    if (tid < 256) {
      const float v =
          rsl[tid] + rsl[256 + tid] + rsl[512 + tid] + rsl[768 + tid];
      atomicAdd(&rs[m0 + tid], v);
    }
  }
}

// ---- PV: paired m-tiles p/(15-p) (128 rows), uniform 34 K-tiles; /rowsum ----
__global__ __launch_bounds__(512, 2) void pv_kernel(
    const unsigned short* __restrict__ S, const unsigned short* __restrict__ Vt,
    const float* __restrict__ rowsum, unsigned short* __restrict__ AO) {
  SHARED_TILES4();
  const int bid = blockIdx.x;
  const long long b = bid & 7;       // batch -> XCD pin
  const int r = bid >> 3;            // 0..31
  const int p = r & 7;
  const int n0 = (r >> 3) * 256;
  const unsigned short* Sb = S + b * (long long)SS * SS;
  const unsigned short* Vb = Vt + b * SH;
  const float* rs = rowsum + b * SS;
  TC t = tc_setup<4>();

  for (int pass = 0; pass < 2; ++pass) {
    const int mi0 = pass ? 15 - p : p;
    const int m0 = mi0 * 128;
    const int NT = 2 * (mi0 + 1);
    const unsigned short* pA = Sb + (long long)(m0 + t.rowt) * SS + t.colg;
    const unsigned short* pB = Vb + (long long)(n0 + t.rowt) * SS + t.colg;
    f32x4 acc[4][4] = {};
    run_tile<4>(pA, pB, SS, SS, NT, As0, As1, Bs0, Bs1, t.wid, t.rA, t.rB,
                t.cb, acc);
#pragma unroll
    for (int mi = 0; mi < 4; ++mi)
#pragma unroll
      for (int j = 0; j < 4; ++j) {
        const int gm = m0 + t.wm * 64 + mi * 16 + t.rr + j;
        const float inv = 1.0f / rs[gm];
#pragma unroll
        for (int ni = 0; ni < 4; ++ni) {
          const int gn = n0 + t.wn * 64 + ni * 16 + t.ccl;
          AO[(b * SS + gm) * (long long)HD + gn] = f2bf(acc[mi][ni][j] * inv);
        }
      }
  }
}

// ---- output projection: f32 out ----
__global__ __launch_bounds__(512, 2) void oproj_kernel(
    const unsigned short* __restrict__ AO, const unsigned short* __restrict__ W,
    const float* __restrict__ bo, float* __restrict__ out) {
  SHARED_TILES8();
  const int lin = blockIdx.x;
  const int swz = (lin & 7) * 32 + (lin >> 3);
  const int n0 = (swz & 3) * 256, m0 = (swz >> 2) * 256;
  TC t = tc_setup<8>();
  const unsigned short* pA = AO + (long long)(m0 + t.rowt) * HD + t.colg;
  const unsigned short* pB = W + (long long)(n0 + t.rowt) * HD + t.colg;
  f32x4 acc[8][4] = {};
  run_tile<8>(pA, pB, HD, HD, 16, As0, As1, Bs0, Bs1, t.wid, t.rA, t.rB, t.cb, acc);
#pragma unroll
  for (int mi = 0; mi < 8; ++mi)
#pragma unroll
    for (int ni = 0; ni < 4; ++ni) {
      const int gn = n0 + t.wn * 64 + ni * 16 + t.ccl;
      const float bias = bo[gn];
#pragma unroll
      for (int j = 0; j < 4; ++j) {
        const int gm = m0 + t.wm * 128 + mi * 16 + t.rr + j;
        out[(long long)gm * HD + gn] = acc[mi][ni][j] + bias;
      }
    }
}

// ---- single cast dispatch: x + 4 weights -> bf16, rowsum -> 0 ----
__global__ __launch_bounds__(256) void cast_all(
    const float* __restrict__ x, const float* __restrict__ wq,
    const float* __restrict__ wk, const float* __restrict__ wv,
    const float* __restrict__ wo, unsigned short* __restrict__ xb,
    unsigned short* __restrict__ wqkb, unsigned short* __restrict__ wvb,
    unsigned short* __restrict__ wob, float* __restrict__ rowsum) {
  const int NX4 = (int)((long long)BB * SS * HD / 4);  // 4194304
  const int W4 = HD * HD / 4;                          // 262144
  const int RS4 = BB * SS / 4;                         // 4096
  const int TOT = NX4 + 4 * W4 + RS4;
  int idx = blockIdx.x * blockDim.x + threadIdx.x;
  const int stride = gridDim.x * blockDim.x;
  for (int u = idx; u < TOT; u += stride) {
    if (u >= NX4 + 4 * W4) {
      *reinterpret_cast<float4*>(rowsum + (u - NX4 - 4 * W4) * 4) =
          make_float4(0.f, 0.f, 0.f, 0.f);
      continue;
    }
    const float* src;
    unsigned short* dst;
    int off;
    if (u < NX4) {
      src = x; dst = xb; off = u;
    } else {
      const int v = u - NX4;
      const int seg = v >> 18;
      off = v & (W4 - 1);
      if (seg == 0) { src = wq; dst = wqkb; }
      else if (seg == 1) { src = wk; dst = wqkb + HD * HD; }
      else if (seg == 2) { src = wv; dst = wvb; }
      else { src = wo; dst = wob; }
    }
    float4 f = *reinterpret_cast<const float4*>(src + off * 4);
    ushort4 o;
    o.x = f2bf(f.x); o.y = f2bf(f.y); o.z = f2bf(f.z); o.w = f2bf(f.w);
    *reinterpret_cast<ushort4*>(dst + off * 4) = o;
  }
}

extern "C" void kernel_launch(void* const* d_in, const int* in_sizes, int n_in,
                              void* d_out, int out_size, void* d_ws, size_t ws_size,
                              hipStream_t stream) {
  const float* x = (const float*)d_in[0];
  const int* amask = (const int*)d_in[1];
  const float* wq = (const float*)d_in[2];
  const float* bq = (const float*)d_in[3];
  const float* wk = (const float*)d_in[4];
  const float* bk = (const float*)d_in[5];
  const float* wv = (const float*)d_in[6];
  const float* bv = (const float*)d_in[7];
  const float* wo = (const float*)d_in[8];
  const float* bo = (const float*)d_in[9];
  float* out = (float*)d_out;

  const long long NX = (long long)BB * SS * HD;
  char* p = (char*)d_ws;
  unsigned short* xb = (unsigned short*)p;    p += NX * 2;
  unsigned short* wqkb = (unsigned short*)p;  p += 2LL * HD * HD * 2;
  unsigned short* wvb = (unsigned short*)p;   p += (long long)HD * HD * 2;
  unsigned short* wob = (unsigned short*)p;   p += (long long)HD * HD * 2;
  unsigned short* Qb = (unsigned short*)p;    p += NX * 2;
  unsigned short* Kb = (unsigned short*)p;    p += NX * 2;
  unsigned short* Vtb = (unsigned short*)p;   p += NX * 2;  // [b][d][s]
  unsigned short* Sb = (unsigned short*)p;    p += (long long)BB * SS * SS * 2;
  float* rowsum = (float*)p;                  p += (long long)BB * SS * 4;
  unsigned short* AOb = xb;  // alias: x dead after QK + mid projections

  cast_all<<<dim3(2048), 256, 0, stream>>>(x, wq, wk, wv, wo, xb, wqkb, wvb,
                                           wob, rowsum);

  qk_kernel<<<dim3(8, 64), 512, 0, stream>>>(xb, wqkb, bq, bk, Qb, Kb);

  mid_kernel<<<dim3(544), 512, 0, stream>>>(wvb, xb, bv, Vtb, Qb, Kb, amask,
                                            Sb, rowsum);

  pv_kernel<<<dim3(256), 512, 0, stream>>>(Sb, Vtb, rowsum, AOb);

  oproj_kernel<<<dim3(256), 512, 0, stream>>>(AOb, wob, bo, out);
}